// Round 4
// baseline (4192.365 us; speedup 1.0000x reference)
//
#include <hip/hip_runtime.h>
#include <hip/hip_bf16.h>
#include <hip/hip_cooperative_groups.h>

#define Bv 8
#define Tv 16
#define Hv 64
#define Wv 64
#define Cv 16
#define HID 64
#define PH 66   // spatially padded (1-px halo)

namespace cg = cooperative_groups;

typedef short short8 __attribute__((ext_vector_type(8)));
typedef float f32x4 __attribute__((ext_vector_type(4)));
typedef unsigned short u16x8 __attribute__((ext_vector_type(8)));

__device__ __forceinline__ unsigned short f2bf(float x) {
  union { float f; unsigned int u; } v; v.f = x;
  unsigned int r = v.u + 0x7FFF + ((v.u >> 16) & 1);   // RNE
  return (unsigned short)(r >> 16);
}
__device__ __forceinline__ float sigmoid_f(float x) {
  return 1.f / (1.f + __expf(-x));
}
__device__ __forceinline__ float tanh_f(float x) {
  float e = __expf(2.f * x);
  return 1.f - 2.f / (e + 1.f);
}

// ---- weight re-layouts: fp32 [3,3,CI,256] -> bf16 [chunk][col'][32]
// col' = wn*64 + g*16 + c  <->  orig col = g*64 + wn*16 + c   (wave-local gate fusion)
__global__ void relayout_w0(const float* __restrict__ W0, unsigned short* __restrict__ out) {
  int o = blockIdx.x * 256 + threadIdx.x;            // 27*8192 = 221184
  if (o >= 27 * 8192) return;
  int chunk = o >> 13, rem = o & 8191;
  int colp = rem >> 5, kk = rem & 31;
  int tap = chunk / 3, cgi = chunk - tap * 3;
  int wn = colp >> 6, g = (colp >> 4) & 3, c = colp & 15;
  int col = g * 64 + wn * 16 + c;
  int p = cgi * 32 + kk;                             // padded ci: 0..15 x, 16..31 pad, 32..95 h
  float v = 0.f;
  if (p < 16)        v = W0[(size_t)(tap * 80 + p) * 256 + col];
  else if (p >= 32)  v = W0[(size_t)(tap * 80 + (p - 16)) * 256 + col];
  out[o] = f2bf(v);
}
__global__ void relayout_w1(const float* __restrict__ W1, unsigned short* __restrict__ out) {
  int o = blockIdx.x * 256 + threadIdx.x;            // 36*8192 = 294912
  if (o >= 36 * 8192) return;
  int chunk = o >> 13, rem = o & 8191;
  int colp = rem >> 5, kk = rem & 31;
  int tap = chunk >> 2, cgi = chunk & 3;
  int wn = colp >> 6, g = (colp >> 4) & 3, c = colp & 15;
  int col = g * 64 + wn * 16 + c;
  out[o] = f2bf(W1[(size_t)(tap * 128 + cgi * 32 + kk) * 256 + col]);
}

// ---- in-kernel x conversion: one timestep into padded bf16 [b][66][66][32]
__device__ __forceinline__ void convert_tile(const float* __restrict__ enc, int t,
                                             unsigned short* __restrict__ xb,
                                             int gid, int tid) {
  if (tid < 128) {
    int px = gid * 128 + tid;                        // 0..32767
    int b = px >> 12, pix = px & 4095;
    int y = pix >> 6, x = pix & 63;
    const float* s = enc + ((size_t)(b * Tv + t) * 4096 + pix) * 16;
    float4 f0 = *(const float4*)(s);
    float4 f1 = *(const float4*)(s + 4);
    float4 f2 = *(const float4*)(s + 8);
    float4 f3 = *(const float4*)(s + 12);
    u16x8 o0, o1, z = {};
    o0[0]=f2bf(f0.x); o0[1]=f2bf(f0.y); o0[2]=f2bf(f0.z); o0[3]=f2bf(f0.w);
    o0[4]=f2bf(f1.x); o0[5]=f2bf(f1.y); o0[6]=f2bf(f1.z); o0[7]=f2bf(f1.w);
    o1[0]=f2bf(f2.x); o1[1]=f2bf(f2.y); o1[2]=f2bf(f2.z); o1[3]=f2bf(f2.w);
    o1[4]=f2bf(f3.x); o1[5]=f2bf(f3.y); o1[6]=f2bf(f3.z); o1[7]=f2bf(f3.w);
    unsigned short* d = xb + ((size_t)((b * PH + y + 1) * PH) + (x + 1)) * 32;
    *(u16x8*)(d)      = o0;
    *(u16x8*)(d + 8)  = o1;
    *(u16x8*)(d + 16) = z;
    *(u16x8*)(d + 24) = z;
  }
}

// ---- one ConvLSTM cell step (implicit-GEMM MFMA + gates), c-state in registers.
// Wave = 64 px x 16 hid x 4 gates. CELL=0: A0 = x_bf(32ch), A1 = h0(64ch), 27 chunks.
// CELL=1: A0 = h0, A1 = h1, 36 chunks. Depth-2 register prefetch (all loads L2-warm).
template<int CELL>
__device__ __forceinline__ void cell_body(
    const unsigned short* __restrict__ A0, const unsigned short* __restrict__ A1,
    const unsigned short* __restrict__ Wr, const float* bi,
    float (&cst)[4][4],
    unsigned short* __restrict__ hout, float* __restrict__ h1f, float* __restrict__ c1f,
    const int* pixpad, int wm, int wn, int r, int kg, int j, int b, int by, int bx)
{
  constexpr int CG = (CELL == 0) ? 3 : 4;
  constexpr int NC = 9 * CG;
  const char* bases[2] = {(const char*)A0, (const char*)A1};
  unsigned int offs[CG][4];
#pragma unroll
  for (int mi = 0; mi < 4; ++mi) {
#pragma unroll
    for (int cgi = 0; cgi < CG; ++cgi) {
      int chb = (CELL == 0) ? (cgi == 0 ? 64 : 128) : 128;   // bytes per pixel-row
      int cho = (CELL == 0) ? (cgi == 2 ? 64 : 0) : ((cgi & 1) * 64);
      offs[cgi][mi] = (unsigned)(pixpad[mi] * chb + cho + kg * 16);
    }
  }
  const unsigned int boff = (unsigned)((wn * 64 + r) * 64 + kg * 16);

  f32x4 acc[4][4] = {};
  short8 af[2][4], bfv[2][4];

  auto LD = [&](int cc, int pp) {
    int tap = cc / CG, cgi = cc - tap * CG;
    int ky = tap / 3, kx = tap - ky * 3;
    int chb = (CELL == 0) ? (cgi == 0 ? 64 : 128) : 128;
    int bs  = (CELL == 0) ? (cgi == 0 ? 0 : 1) : (cgi >> 1);
    unsigned int toff = (unsigned)((ky * PH + kx) * chb);
#pragma unroll
    for (int mi = 0; mi < 4; ++mi)
      af[pp][mi] = *(const short8*)(bases[bs] + offs[cgi][mi] + toff);
    const char* wp = (const char*)Wr + (size_t)cc * 16384 + boff;
#pragma unroll
    for (int g = 0; g < 4; ++g)
      bfv[pp][g] = *(const short8*)(wp + g * 1024);
  };

  LD(0, 0);
#pragma unroll
  for (int cc = 0; cc < NC; ++cc) {
    if (cc + 1 < NC) LD(cc + 1, (cc + 1) & 1);
    const int pp = cc & 1;
#pragma unroll
    for (int mi = 0; mi < 4; ++mi)
#pragma unroll
      for (int g = 0; g < 4; ++g)
        acc[mi][g] = __builtin_amdgcn_mfma_f32_16x16x32_bf16(
            af[pp][mi], bfv[pp][g], acc[mi][g], 0, 0, 0);
  }

  // gates: this wave owns hid j = wn*16+r for all 4 gates; c-state in regs
#pragma unroll
  for (int mi = 0; mi < 4; ++mi) {
#pragma unroll
    for (int rg = 0; rg < 4; ++rg) {
      int p = wm * 64 + mi * 16 + kg * 4 + rg;       // C/D row = (lane>>4)*4 + reg
      int y = by * 16 + (p >> 3), x = bx * 8 + (p & 7);
      float zi = acc[mi][0][rg] + bi[0];
      float zf = acc[mi][1][rg] + bi[1];
      float zo = acc[mi][2][rg] + bi[2];
      float zg = acc[mi][3][rg] + bi[3];
      float co = cst[mi][rg];
      float cn = sigmoid_f(zf) * co + sigmoid_f(zi) * tanh_f(zg);
      float hn = sigmoid_f(zo) * tanh_f(cn);
      cst[mi][rg] = cn;
      hout[((size_t)((b * PH + y + 1) * PH) + (x + 1)) * HID + j] = f2bf(hn);
      if (CELL == 1 && h1f != nullptr) {
        size_t ci = ((size_t)((b * Hv + y) * Wv) + x) * HID + j;
        h1f[ci] = hn;
        c1f[ci] = cn;
      }
    }
  }
}

// ---- the whole 16-step, 2-cell scan in ONE cooperative kernel.
// grid = 256 blocks (1/CU), block = 512 thr (8 waves). Block tile = 16x8 px.
__global__ __launch_bounds__(512, 2)
void encoder_scan(const float* __restrict__ enc,
                  unsigned short* __restrict__ xb0, unsigned short* __restrict__ xb1,
                  const unsigned short* __restrict__ w0r, const unsigned short* __restrict__ w1r,
                  const float* __restrict__ b0, const float* __restrict__ b1,
                  unsigned short* __restrict__ h0a, unsigned short* __restrict__ h0b,
                  unsigned short* __restrict__ h1a, unsigned short* __restrict__ h1b,
                  float* __restrict__ h1f, float* __restrict__ c1f)
{
  cg::grid_group grid = cg::this_grid();
  const int tid = threadIdx.x;
  const int gid = blockIdx.x;
  const int bx = gid & 7, by = (gid >> 3) & 3, b = gid >> 5;
  const int l = tid & 63, w = tid >> 6;
  const int wm = w >> 2, wn = w & 3;
  const int r = l & 15, kg = l >> 4;
  const int j = wn * 16 + r;

  int pixpad[4];
#pragma unroll
  for (int mi = 0; mi < 4; ++mi) {
    int p = wm * 64 + mi * 16 + r;
    int y = by * 16 + (p >> 3), x = bx * 8 + (p & 7);
    pixpad[mi] = (b * PH + y) * PH + x;              // tap(0,0) in padded coords
  }
  float bi0[4], bi1[4];
#pragma unroll
  for (int g = 0; g < 4; ++g) { bi0[g] = b0[g * 64 + j]; bi1[g] = b1[g * 64 + j]; }

  float c0st[4][4] = {};
  float c1st[4][4] = {};

  unsigned short* xbuf[2]  = {xb0, xb1};
  unsigned short* h0buf[2] = {h0a, h0b};
  unsigned short* h1buf[2] = {h1a, h1b};

  convert_tile(enc, 0, xbuf[0], gid, tid);
  grid.sync();

#pragma unroll 1
  for (int t = 0; t < Tv; ++t) {
    const int cur = t & 1, prv = cur ^ 1;
    const bool last = (t == Tv - 1);

    cell_body<0>(xbuf[cur], h0buf[prv], w0r, bi0, c0st, h0buf[cur],
                 nullptr, nullptr, pixpad, wm, wn, r, kg, j, b, by, bx);
    if (t + 1 < Tv) convert_tile(enc, t + 1, xbuf[prv], gid, tid);
    grid.sync();                                     // h0(t) + x(t+1) visible

    cell_body<1>(h0buf[cur], h1buf[prv], w1r, bi1, c1st, h1buf[cur],
                 last ? h1f : nullptr, last ? c1f : nullptr,
                 pixpad, wm, wn, r, kg, j, b, by, bx);
    grid.sync();                                     // h1(t) visible
  }
}

extern "C" void kernel_launch(void* const* d_in, const int* in_sizes, int n_in,
                              void* d_out, int out_size, void* d_ws, size_t ws_size,
                              hipStream_t stream) {
  const float* enc = (const float*)d_in[0];
  const float* W0  = (const float*)d_in[1];
  const float* b0  = (const float*)d_in[2];
  const float* W1  = (const float*)d_in[3];
  const float* b1  = (const float*)d_in[4];

  float* out = (float*)d_out;
  const size_t NST = (size_t)Bv * Hv * Wv * HID;     // 2,097,152
  float* h1f = out;                                   // final h1 (fp32)
  float* c1f = out + NST;                             // final c1 (fp32)

  char* ws = (char*)d_ws;
  const size_t SZ_H = (size_t)Bv * PH * PH * HID * 2;   // 4,460,544
  const size_t SZ_X = (size_t)Bv * PH * PH * 32 * 2;    // 2,230,272
  unsigned short* h0a = (unsigned short*)(ws);
  unsigned short* h0b = (unsigned short*)(ws + SZ_H);
  unsigned short* h1a = (unsigned short*)(ws + 2 * SZ_H);
  unsigned short* h1b = (unsigned short*)(ws + 3 * SZ_H);
  unsigned short* xb0 = (unsigned short*)(ws + 4 * SZ_H);
  unsigned short* xb1 = (unsigned short*)(ws + 4 * SZ_H + SZ_X);
  unsigned short* w0r = (unsigned short*)(ws + 4 * SZ_H + 2 * SZ_X);
  unsigned short* w1r = (unsigned short*)(ws + 4 * SZ_H + 2 * SZ_X + 27 * 8192 * 2);

  // zero h buffers (t=0 state + halos) and x buffers (halos + pad channels)
  hipMemsetAsync(ws, 0, 4 * SZ_H + 2 * SZ_X, stream);

  relayout_w0<<<864, 256, 0, stream>>>(W0, w0r);
  relayout_w1<<<1152, 256, 0, stream>>>(W1, w1r);

  void* args[13] = {(void*)&enc, (void*)&xb0, (void*)&xb1, (void*)&w0r, (void*)&w1r,
                    (void*)&b0, (void*)&b1, (void*)&h0a, (void*)&h0b,
                    (void*)&h1a, (void*)&h1b, (void*)&h1f, (void*)&c1f};
  hipLaunchCooperativeKernel(encoder_scan, dim3(256), dim3(512), args, 0, stream);
}

// Round 5
// 1305.289 us; speedup vs baseline: 3.2118x; 3.2118x over previous
//
#include <hip/hip_runtime.h>
#include <hip/hip_bf16.h>

#define Bv 8
#define Tv 16
#define Hv 64
#define Wv 64
#define Cv 16
#define HID 64
#define PH 66   // spatially padded (1-px halo)

typedef short short8 __attribute__((ext_vector_type(8)));
typedef float f32x4 __attribute__((ext_vector_type(4)));
typedef unsigned short u16x8 __attribute__((ext_vector_type(8)));

__device__ __forceinline__ unsigned short f2bf(float x) {
  union { float f; unsigned int u; } v; v.f = x;
  unsigned int r = v.u + 0x7FFF + ((v.u >> 16) & 1);   // RNE
  return (unsigned short)(r >> 16);
}
__device__ __forceinline__ float sigmoid_f(float x) {
  return 1.f / (1.f + __expf(-x));
}
__device__ __forceinline__ float tanh_f(float x) {
  float e = __expf(2.f * x);
  return 1.f - 2.f / (e + 1.f);
}

// ---- weight re-layouts: fp32 [3,3,CI,256] -> bf16 lane-contiguous chunks.
// Chunk cc (16KB): [wn(4)][g(4)][lane(64)][e(8)] where lane l=(kg*16+r) holds
// B[k=kg*8+e][col' = wn*64+g*16+r], orig col = g*64 + wn*16 + r.
__global__ void relayout_w0(const float* __restrict__ W0, unsigned short* __restrict__ out) {
  int o = blockIdx.x * 256 + threadIdx.x;            // 27*8192 = 221184
  if (o >= 27 * 8192) return;
  int cc = o >> 13, t = o & 8191;
  int wn = t >> 11, t2 = t & 2047;
  int g = t2 >> 9, t3 = t2 & 511;
  int l = t3 >> 3, e = t3 & 7;
  int kg = l >> 4, r = l & 15;
  int k = kg * 8 + e;
  int col = g * 64 + wn * 16 + r;
  int tap = cc / 3, cgi = cc - tap * 3;
  int p = cgi * 32 + k;                              // padded ci: 0..15 x, 16..31 pad, 32..95 h
  float v = 0.f;
  if (p < 16)        v = W0[(size_t)(tap * 80 + p) * 256 + col];
  else if (p >= 32)  v = W0[(size_t)(tap * 80 + (p - 16)) * 256 + col];
  out[o] = f2bf(v);
}
__global__ void relayout_w1(const float* __restrict__ W1, unsigned short* __restrict__ out) {
  int o = blockIdx.x * 256 + threadIdx.x;            // 36*8192 = 294912
  if (o >= 36 * 8192) return;
  int cc = o >> 13, t = o & 8191;
  int wn = t >> 11, t2 = t & 2047;
  int g = t2 >> 9, t3 = t2 & 511;
  int l = t3 >> 3, e = t3 & 7;
  int kg = l >> 4, r = l & 15;
  int k = kg * 8 + e;
  int col = g * 64 + wn * 16 + r;
  int tap = cc >> 2, cgi = cc & 3;
  out[o] = f2bf(W1[(size_t)(tap * 128 + cgi * 32 + k) * 256 + col]);
}

// ---- t=0 x conversion: enc fp32 -> padded bf16 [b][66][66][32] (pads pre-zeroed)
__global__ void convert_x0(const float* __restrict__ enc, unsigned short* __restrict__ xb) {
  int idx = blockIdx.x * 256 + threadIdx.x;          // 32768
  int b = idx >> 12, pix = idx & 4095;
  int y = pix >> 6, x = pix & 63;
  const float* s = enc + ((size_t)(b * Tv + 0) * 4096 + pix) * 16;
  float4 f0 = *(const float4*)(s);
  float4 f1 = *(const float4*)(s + 4);
  float4 f2 = *(const float4*)(s + 8);
  float4 f3 = *(const float4*)(s + 12);
  u16x8 o0, o1;
  o0[0]=f2bf(f0.x); o0[1]=f2bf(f0.y); o0[2]=f2bf(f0.z); o0[3]=f2bf(f0.w);
  o0[4]=f2bf(f1.x); o0[5]=f2bf(f1.y); o0[6]=f2bf(f1.z); o0[7]=f2bf(f1.w);
  o1[0]=f2bf(f2.x); o1[1]=f2bf(f2.y); o1[2]=f2bf(f2.z); o1[3]=f2bf(f2.w);
  o1[4]=f2bf(f3.x); o1[5]=f2bf(f3.y); o1[6]=f2bf(f3.z); o1[7]=f2bf(f3.w);
  unsigned short* d = xb + ((size_t)((b * PH + y + 1) * PH) + (x + 1)) * 32;
  *(u16x8*)(d)     = o0;
  *(u16x8*)(d + 8) = o1;
}

// ---- fused ConvLSTM cell step: LDS-staged implicit-GEMM MFMA + gates.
// Block: 128 px (16x8) x 256 gate-cols, 8 waves. Wave = 64px x 16hid x 4gates.
// Per-wave private LDS slice 16KB = 2 x (A 4KB + W 4KB); zero barriers.
// Pipeline per chunk: vmcnt(8) -> ds_read -> MFMA(prev) -> lgkmcnt(0) -> issue(c+2).
template<int CELL>
__global__ __launch_bounds__(512, 2)
void cell_mfma(const unsigned short* __restrict__ A0, const unsigned short* __restrict__ A1,
               const unsigned short* __restrict__ Wr, const float* __restrict__ bias,
               float* __restrict__ cbuf, unsigned short* __restrict__ hout,
               float* __restrict__ h1f, float* __restrict__ c1f,
               const float* __restrict__ enc, int tnext, unsigned short* __restrict__ xnext)
{
  constexpr int CG = (CELL == 0) ? 3 : 4;
  constexpr int NC = 9 * CG;
  extern __shared__ char lds[];                      // 8 waves x 16KB

  const int tid = threadIdx.x;
  const int l = tid & 63, w = tid >> 6;
  const int wm = w >> 2, wn = w & 3;
  const int gid = blockIdx.x;
  const int bx = gid & 7, by = (gid >> 3) & 3, b = gid >> 5;
  const int r = l & 15, kg = l >> 4;
  const int j = wn * 16 + r;

  const char* bases[2] = {(const char*)A0, (const char*)A1};
  int pixpad[4];
  unsigned offs[CG][4];
#pragma unroll
  for (int mi = 0; mi < 4; ++mi) {
    int p = wm * 64 + mi * 16 + r;
    int y = by * 16 + (p >> 3), x = bx * 8 + (p & 7);
    pixpad[mi] = (b * PH + y) * PH + x;              // tap(0,0) in padded coords
#pragma unroll
    for (int cgi = 0; cgi < CG; ++cgi) {
      int chb = (CELL == 0) ? (cgi == 0 ? 64 : 128) : 128;   // bytes per pixel-row
      int cho = (CELL == 0) ? (cgi == 2 ? 64 : 0) : ((cgi & 1) * 64);
      offs[cgi][mi] = (unsigned)(pixpad[mi] * chb + cho + kg * 16);
    }
  }

  // ---- early loads (bias + c state), fenced so loop vmcnt counts stay exact
  float bi[4];
#pragma unroll
  for (int g = 0; g < 4; ++g) bi[g] = bias[g * 64 + j];
  float cpre[4][4];
#pragma unroll
  for (int mi = 0; mi < 4; ++mi) {
#pragma unroll
    for (int rg = 0; rg < 4; ++rg) {
      int p = wm * 64 + mi * 16 + kg * 4 + rg;
      int y = by * 16 + (p >> 3), x = bx * 8 + (p & 7);
      cpre[mi][rg] = cbuf[((size_t)((b * Hv + y) * Wv) + x) * HID + j];
    }
  }
  asm volatile("s_waitcnt vmcnt(0)" ::: "memory");
  __builtin_amdgcn_sched_barrier(0);

  char* slice = lds + w * 16384;                     // wave-uniform

  auto ISSUE = [&](int cc, int pp) {
    char* dst = slice + pp * 8192;
    int tap = cc / CG, cgi = cc - tap * CG;
    int ky = tap / 3, kx = tap - ky * 3;
    int chb = (CELL == 0) ? (cgi == 0 ? 64 : 128) : 128;
    int bs  = (CELL == 0) ? (cgi == 0 ? 0 : 1) : (cgi >> 1);
    unsigned toff = (unsigned)((ky * PH + kx) * chb);
    const char* base = bases[bs];
#pragma unroll
    for (int mi = 0; mi < 4; ++mi)
      __builtin_amdgcn_global_load_lds(
          (const unsigned int*)(base + offs[cgi][mi] + toff),
          (unsigned int*)(dst + mi * 1024), 16, 0, 0);
    const char* wp = (const char*)Wr + (size_t)cc * 16384 + wn * 4096 + l * 16;
#pragma unroll
    for (int g = 0; g < 4; ++g)
      __builtin_amdgcn_global_load_lds(
          (const unsigned int*)(wp + g * 1024),
          (unsigned int*)(dst + 4096 + g * 1024), 16, 0, 0);
  };

  f32x4 acc[4][4] = {};
  short8 af[2][4], bfv[2][4];

  ISSUE(0, 0);
  ISSUE(1, 1);
#pragma unroll
  for (int cc = 0; cc < NC; ++cc) {
    if (cc == NC - 1) { asm volatile("s_waitcnt vmcnt(0)" ::: "memory"); }
    else              { asm volatile("s_waitcnt vmcnt(8)" ::: "memory"); }
    __builtin_amdgcn_sched_barrier(0);
    const int q = cc & 1;
    const char* src = slice + q * 8192;
#pragma unroll
    for (int mi = 0; mi < 4; ++mi) af[q][mi] = *(const short8*)(src + mi * 1024 + l * 16);
#pragma unroll
    for (int g = 0; g < 4; ++g)  bfv[q][g] = *(const short8*)(src + 4096 + g * 1024 + l * 16);
    if (cc > 0) {
      const int qp = q ^ 1;
#pragma unroll
      for (int mi = 0; mi < 4; ++mi)
#pragma unroll
        for (int g = 0; g < 4; ++g)
          acc[mi][g] = __builtin_amdgcn_mfma_f32_16x16x32_bf16(
              af[qp][mi], bfv[qp][g], acc[mi][g], 0, 0, 0);
    }
    asm volatile("s_waitcnt lgkmcnt(0)" ::: "memory");
    __builtin_amdgcn_sched_barrier(0);
    if (cc + 2 < NC) ISSUE(cc + 2, q);
  }
  {
    const int qp = (NC - 1) & 1;
#pragma unroll
    for (int mi = 0; mi < 4; ++mi)
#pragma unroll
      for (int g = 0; g < 4; ++g)
        acc[mi][g] = __builtin_amdgcn_mfma_f32_16x16x32_bf16(
            af[qp][mi], bfv[qp][g], acc[qp == 0 ? mi : mi][g], 0, 0, 0);
  }

  // ---- gates: this wave owns hid j for all 4 gates; c from regs
#pragma unroll
  for (int mi = 0; mi < 4; ++mi) {
#pragma unroll
    for (int rg = 0; rg < 4; ++rg) {
      int p = wm * 64 + mi * 16 + kg * 4 + rg;       // C/D row = (lane>>4)*4 + reg
      int y = by * 16 + (p >> 3), x = bx * 8 + (p & 7);
      float zi = acc[mi][0][rg] + bi[0];
      float zf = acc[mi][1][rg] + bi[1];
      float zo = acc[mi][2][rg] + bi[2];
      float zg = acc[mi][3][rg] + bi[3];
      float co = cpre[mi][rg];
      float cn = sigmoid_f(zf) * co + sigmoid_f(zi) * tanh_f(zg);
      float hn = sigmoid_f(zo) * tanh_f(cn);
      size_t ci = ((size_t)((b * Hv + y) * Wv) + x) * HID + j;
      cbuf[ci] = cn;
      hout[((size_t)((b * PH + y + 1) * PH) + (x + 1)) * HID + j] = f2bf(hn);
      if (CELL == 1 && h1f != nullptr) {
        h1f[ci] = hn;
        c1f[ci] = cn;
      }
    }
  }

  // ---- tail: convert x(tnext) for the next cell0 (cell1 only)
  if (CELL == 1 && tnext < Tv) {
    int px = gid * 128 + (tid >> 2), q4 = tid & 3;
    int bb = px >> 12, pix = px & 4095;
    int y = pix >> 6, x = pix & 63;
    const float* s = enc + ((size_t)(bb * Tv + tnext) * 4096 + pix) * 16 + q4 * 4;
    float4 f = *(const float4*)s;
    unsigned short* d = xnext + ((size_t)((bb * PH + y + 1) * PH) + (x + 1)) * 32 + q4 * 4;
    d[0] = f2bf(f.x); d[1] = f2bf(f.y); d[2] = f2bf(f.z); d[3] = f2bf(f.w);
  }
}

extern "C" void kernel_launch(void* const* d_in, const int* in_sizes, int n_in,
                              void* d_out, int out_size, void* d_ws, size_t ws_size,
                              hipStream_t stream) {
  const float* enc = (const float*)d_in[0];
  const float* W0  = (const float*)d_in[1];
  const float* b0  = (const float*)d_in[2];
  const float* W1  = (const float*)d_in[3];
  const float* b1  = (const float*)d_in[4];

  float* out = (float*)d_out;
  const size_t NST = (size_t)Bv * Hv * Wv * HID;     // 2,097,152
  float* h1f = out;                                   // final h1 (fp32)
  float* c1  = out + NST;                             // c1 running state (fp32, in-place)

  char* ws = (char*)d_ws;
  const size_t SZ_C = NST * 4;                        // 8,388,608
  const size_t SZ_H = (size_t)Bv * PH * PH * HID * 2; // 4,460,544
  const size_t SZ_X = (size_t)Bv * PH * PH * 32 * 2;  // 2,230,272
  float*          c0  = (float*)ws;
  unsigned short* h0a = (unsigned short*)(ws + SZ_C);
  unsigned short* h0b = (unsigned short*)(ws + SZ_C + SZ_H);
  unsigned short* h1a = (unsigned short*)(ws + SZ_C + 2 * SZ_H);
  unsigned short* h1b = (unsigned short*)(ws + SZ_C + 3 * SZ_H);
  unsigned short* xb  = (unsigned short*)(ws + SZ_C + 4 * SZ_H);
  unsigned short* w0r = (unsigned short*)(ws + SZ_C + 4 * SZ_H + SZ_X);
  unsigned short* w1r = (unsigned short*)(ws + SZ_C + 4 * SZ_H + SZ_X + (size_t)27 * 16384);

  static bool attr_done = false;   // idempotent attribute set (not state-dependent work)
  hipFuncSetAttribute((const void*)cell_mfma<0>, hipFuncAttributeMaxDynamicSharedMemorySize, 131072);
  hipFuncSetAttribute((const void*)cell_mfma<1>, hipFuncAttributeMaxDynamicSharedMemorySize, 131072);
  (void)attr_done;

  // zero c0 + h buffers + x buffer (t=0 state, halos, pad channels); zero c1 in d_out
  hipMemsetAsync(ws, 0, SZ_C + 4 * SZ_H + SZ_X, stream);
  hipMemsetAsync(c1, 0, SZ_C, stream);

  relayout_w0<<<864, 256, 0, stream>>>(W0, w0r);
  relayout_w1<<<1152, 256, 0, stream>>>(W1, w1r);
  convert_x0<<<128, 256, 0, stream>>>(enc, xb);

  dim3 grid(256), block(512);
  for (int t = 0; t < Tv; ++t) {
    const bool last = (t == Tv - 1);
    unsigned short* h0r = (t & 1) ? h0b : h0a;
    unsigned short* h0w = (t & 1) ? h0a : h0b;
    unsigned short* h1r = (t & 1) ? h1b : h1a;
    unsigned short* h1w = (t & 1) ? h1a : h1b;
    cell_mfma<0><<<grid, block, 131072, stream>>>(
        xb, h0r, w0r, b0, c0, h0w, nullptr, nullptr, nullptr, Tv, nullptr);
    cell_mfma<1><<<grid, block, 131072, stream>>>(
        h0w, h1r, w1r, b1, c1, h1w, last ? h1f : nullptr, last ? (c1) : nullptr,
        enc, t + 1, xb);
  }
}